// Round 1
// baseline (292.212 us; speedup 1.0000x reference)
//
#include <hip/hip_runtime.h>

#define F 2048
#define BATCH 1024
#define NBLK 64   // dim
#define OPD 32    // rows per block
#define IPD 32    // cols per block

// ---------------------------------------------------------------------------
// prep: per weight row r (block i = r/32):
//   w[c] = exp(weight[r,c]) for c in diag block, weight[r,c] for c < i*32, 0 above
//   wsn  = sum w^2 ;  scale = exp(dw[r]) / sqrt(wsn)
//   w_n[r,c] = scale * w[c]   (zero-filled above diag block)
//   exp_blocks[r,p] = exp(dw[r] + weight[r, i*32+p] - 0.5*log(wsn))
// ---------------------------------------------------------------------------
__global__ __launch_bounds__(256) void prep_kernel(
    const float* __restrict__ weight, const float* __restrict__ dw,
    float* __restrict__ w_n, float* __restrict__ exp_blocks)
{
  int r = blockIdx.x;
  int i = r >> 5;
  int lim = (i + 1) * 32;
  int tid = threadIdx.x;
  const float* wrow = weight + (size_t)r * F;

  float ss = 0.f;
  for (int c = tid; c < lim; c += 256) {
    float wv = wrow[c];
    float w = (c >= i * 32) ? __expf(wv) : wv;
    ss += w * w;
  }
  __shared__ float red[256];
  red[tid] = ss;
  __syncthreads();
  for (int s = 128; s > 0; s >>= 1) {
    if (tid < s) red[tid] += red[tid + s];
    __syncthreads();
  }
  float wsn = red[0];
  float dwr = dw[r];
  float scale = __expf(dwr) * rsqrtf(wsn);
  float halflog = 0.5f * __logf(wsn);

  float* onrow = w_n + (size_t)r * F;
  for (int c = tid; c < F; c += 256) {
    float v = 0.f;
    if (c < lim) {
      float wv = wrow[c];
      v = scale * ((c >= i * 32) ? __expf(wv) : wv);
    }
    onrow[c] = v;
  }
  if (tid < 32) {
    float wv = wrow[i * 32 + tid];
    exp_blocks[(size_t)r * 32 + tid] = __expf(dwr + wv - halflog);
  }
}

// ---------------------------------------------------------------------------
// gemm: out[b,r] = sum_c inputs[b,c] * w_n[r,c] + bias[r]
// Both operands K-major (NT GEMM). 64x64 tile, BK=32, 4x4 per thread.
// k-loop only runs to r0+64 (w_n is zero above the diagonal 32-block).
// ---------------------------------------------------------------------------
__global__ __launch_bounds__(256) void gemm_kernel(
    const float* __restrict__ A, const float* __restrict__ W,
    const float* __restrict__ bias, float* __restrict__ out)
{
  __shared__ float As[64][33];
  __shared__ float Ws[64][33];
  int tn = blockIdx.x;   // weight-row (output col) tile: 0..31
  int tmb = blockIdx.y;  // batch tile: 0..15
  int r0 = tn * 64, b0 = tmb * 64;
  int kmax = r0 + 64;    // block-lower-triangular: no data beyond r0+64
  int tid = threadIdx.x;
  int tx = tid & 15, ty = tid >> 4;
  int lc = tid & 31, lr = tid >> 5;

  float acc[4][4] = {{0.f}};
  for (int k0 = 0; k0 < kmax; k0 += 32) {
#pragma unroll
    for (int e = 0; e < 8; ++e)
      As[lr + e * 8][lc] = A[(size_t)(b0 + lr + e * 8) * F + k0 + lc];
#pragma unroll
    for (int e = 0; e < 8; ++e)
      Ws[lr + e * 8][lc] = W[(size_t)(r0 + lr + e * 8) * F + k0 + lc];
    __syncthreads();
#pragma unroll
    for (int kk = 0; kk < 32; ++kk) {
      float a[4], w[4];
#pragma unroll
      for (int m = 0; m < 4; ++m) a[m] = As[ty * 4 + m][kk];
#pragma unroll
      for (int n = 0; n < 4; ++n) w[n] = Ws[tx * 4 + n][kk];
#pragma unroll
      for (int m = 0; m < 4; ++m)
#pragma unroll
        for (int n = 0; n < 4; ++n) acc[m][n] += a[m] * w[n];
    }
    __syncthreads();
  }
#pragma unroll
  for (int m = 0; m < 4; ++m) {
    int b = b0 + ty * 4 + m;
#pragma unroll
    for (int n = 0; n < 4; ++n) {
      int r = r0 + tx * 4 + n;
      out[(size_t)b * F + r] = acc[m][n] + bias[r];
    }
  }
}

// ---------------------------------------------------------------------------
// logdet[b,i,o] = log( sum_p exp_blocks[i,o,p] * exp(grad[b,i,p]) )
// One block handles one i and 8 batches. exp_blocks[i] (32x32) in LDS.
// ---------------------------------------------------------------------------
__global__ __launch_bounds__(256) void logdet_kernel(
    const float* __restrict__ grad, const float* __restrict__ exp_blocks,
    float* __restrict__ ld)
{
  __shared__ float eb[32][33];
  __shared__ float eg[8][32];
  int i = blockIdx.x & 63;
  int bg = blockIdx.x >> 6;
  int tid = threadIdx.x;
  for (int t = tid; t < 1024; t += 256) {
    eb[t >> 5][t & 31] = exp_blocks[(size_t)i * 1024 + t];
  }
  int pair = tid >> 5, p = tid & 31;
  int b = bg * 8 + pair;
  eg[pair][p] = __expf(grad[((size_t)b * 64 + i) * 32 + p]);
  __syncthreads();
  int o = p;
  float s = 0.f;
#pragma unroll
  for (int q = 0; q < 32; ++q) s += eb[o][q] * eg[pair][q];
  ld[((size_t)b * 64 + i) * 32 + o] = __logf(s);
}

// ---------------------------------------------------------------------------
extern "C" void kernel_launch(void* const* d_in, const int* in_sizes, int n_in,
                              void* d_out, int out_size, void* d_ws, size_t ws_size,
                              hipStream_t stream)
{
  const float* inputs = (const float*)d_in[0];
  const float* grad   = (const float*)d_in[1];
  const float* weight = (const float*)d_in[2];
  const float* dw     = (const float*)d_in[3];
  const float* bias   = (const float*)d_in[4];

  float* out = (float*)d_out;                 // 1024*2048
  float* ld  = out + (size_t)BATCH * F;       // 1024*64*32

  float* w_n        = (float*)d_ws;           // 2048*2048 f32 = 16 MiB
  float* exp_blocks = w_n + (size_t)F * F;    // 2048*32 f32 = 256 KiB

  prep_kernel<<<F, 256, 0, stream>>>(weight, dw, w_n, exp_blocks);
  gemm_kernel<<<dim3(32, 16), 256, 0, stream>>>(inputs, w_n, bias, out);
  logdet_kernel<<<64 * 128, 256, 0, stream>>>(grad, exp_blocks, ld);
}

// Round 2
// 120.339 us; speedup vs baseline: 2.4282x; 2.4282x over previous
//
#include <hip/hip_runtime.h>

#define F 2048
#define BATCH 1024

typedef short bf16x8 __attribute__((ext_vector_type(8)));
typedef float f32x4 __attribute__((ext_vector_type(4)));

// round-to-nearest-even f32 -> bf16 (bit trick, finite values only)
__device__ __forceinline__ unsigned short f2bf(float f) {
  unsigned u = __builtin_bit_cast(unsigned, f);
  unsigned r = (u + 0x7fffu + ((u >> 16) & 1u)) >> 16;
  return (unsigned short)r;
}

__device__ __forceinline__ void gload_lds16(const void* g, void* l) {
  __builtin_amdgcn_global_load_lds(
      (const __attribute__((address_space(1))) unsigned int*)g,
      (__attribute__((address_space(3))) unsigned int*)l,
      16, 0, 0);
}

// ---------------------------------------------------------------------------
// convert: inputs f32 -> bf16, 8 elems/thread
// ---------------------------------------------------------------------------
__global__ __launch_bounds__(256) void convert_kernel(
    const float* __restrict__ in, unsigned short* __restrict__ out)
{
  int idx = (blockIdx.x * 256 + threadIdx.x) * 8;
  float4 v0 = *(const float4*)(in + idx);
  float4 v1 = *(const float4*)(in + idx + 4);
  union { unsigned short s[8]; bf16x8 v; } o;
  o.s[0] = f2bf(v0.x); o.s[1] = f2bf(v0.y); o.s[2] = f2bf(v0.z); o.s[3] = f2bf(v0.w);
  o.s[4] = f2bf(v1.x); o.s[5] = f2bf(v1.y); o.s[6] = f2bf(v1.z); o.s[7] = f2bf(v1.w);
  *(bf16x8*)(out + idx) = o.v;
}

// ---------------------------------------------------------------------------
// prep: per weight row r (block i = r/32):
//   w[c] = exp(weight[r,c]) in diag block, weight[r,c] below, 0 above
//   w_n bf16, written only for c < (r&~63)+64 (GEMM reads nothing beyond)
//   exp_blocks[r,p] = exp(dw[r] + weight[r,i*32+p] - 0.5*log(wsn))
// ---------------------------------------------------------------------------
__global__ __launch_bounds__(256) void prep_kernel(
    const float* __restrict__ weight, const float* __restrict__ dw,
    unsigned short* __restrict__ w_n, float* __restrict__ exp_blocks)
{
  int r = blockIdx.x;
  int i = r >> 5;
  int lim = (i + 1) * 32;
  int wlim = (r & ~63) + 64;
  int tid = threadIdx.x;
  const float* wrow = weight + (size_t)r * F;

  float ss = 0.f;
  for (int c = tid; c < lim; c += 256) {
    float wv = wrow[c];
    float w = (c >= i * 32) ? __expf(wv) : wv;
    ss += w * w;
  }
  __shared__ float red[256];
  red[tid] = ss;
  __syncthreads();
  for (int s = 128; s > 0; s >>= 1) {
    if (tid < s) red[tid] += red[tid + s];
    __syncthreads();
  }
  float wsn = red[0];
  float dwr = dw[r];
  float scale = __expf(dwr) * rsqrtf(wsn);
  float halflog = 0.5f * __logf(wsn);

  unsigned short* onrow = w_n + (size_t)r * F;
  for (int c = tid; c < wlim; c += 256) {
    float v = 0.f;
    if (c < lim) {
      float wv = wrow[c];
      v = scale * ((c >= i * 32) ? __expf(wv) : wv);
    }
    onrow[c] = f2bf(v);
  }
  if (tid < 32) {
    float wv = wrow[i * 32 + tid];
    exp_blocks[(size_t)r * 32 + tid] = __expf(dwr + wv - halflog);
  }
}

// ---------------------------------------------------------------------------
// gemm (bf16 MFMA): out[b,r] = sum_c A[b,c]*W[r,c] + bias[r]   (NT, K-major)
// 64x64 tile, BK=64, 4 waves x (32x32 each, 2x2 fragments of 16x16x32).
// Double-buffered LDS via global_load_lds(16B); XOR-swizzled (source-side
// pre-swizzle + swizzled ds_read) to kill the stride-128B bank conflict.
// Triangular K: tile tn runs tn+1 K-steps; block remap pairs tn with 31-tn
// at stride 256 so co-resident blocks per CU have complementary work.
// ---------------------------------------------------------------------------
__global__ __launch_bounds__(256) void gemm_kernel(
    const unsigned short* __restrict__ A, const unsigned short* __restrict__ W,
    const float* __restrict__ bias, float* __restrict__ out)
{
  __shared__ char smem[2][2][8192];  // [buf][A/B][64 rows x 128 B]

  int id = blockIdx.x;
  int tm = id >> 5;
  int tn_raw = id & 31;
  int tn = (tm & 8) ? (31 - tn_raw) : tn_raw;
  int m0 = tm * 64, n0 = tn * 64;
  int nkt = tn + 1;

  int tid = threadIdx.x;
  int lane = tid & 63, wid = tid >> 6;
  int wm = wid >> 1, wn = wid & 1;
  int l15 = lane & 15, lg = lane >> 4;

  // staging constants: per instr s, lane covers row s*8+(lane>>3), slot lane&7;
  // source chunk = slot ^ (row&7) so LDS slot sl holds global chunk sl^(row&7)
  int srow = lane >> 3;
  int schunk = (lane & 7) ^ (srow & 7);

  auto stage = [&](int buf, int kt) {
    size_t kb = (size_t)kt * 128;  // byte offset of K-tile
#pragma unroll
    for (int e = 0; e < 2; ++e) {
      int s = wid * 2 + e;           // 8-row group 0..7
      int row = s * 8 + srow;
      const char* ga = (const char*)A + (size_t)(m0 + row) * (F * 2) + kb + schunk * 16;
      gload_lds16(ga, &smem[buf][0][s * 1024]);
      const char* gb = (const char*)W + (size_t)(n0 + row) * (F * 2) + kb + schunk * 16;
      gload_lds16(gb, &smem[buf][1][s * 1024]);
    }
  };

  f32x4 acc[2][2] = {};

  auto compute = [&](int buf) {
    const char* sA = smem[buf][0];
    const char* sB = smem[buf][1];
    bf16x8 af[2][2], bfr[2][2];
#pragma unroll
    for (int mi = 0; mi < 2; ++mi)
#pragma unroll
      for (int ks = 0; ks < 2; ++ks) {
        int row = wm * 32 + mi * 16 + l15;
        int ch = (ks * 4 + lg) ^ (l15 & 7);
        af[mi][ks] = *(const bf16x8*)(sA + row * 128 + ch * 16);
      }
#pragma unroll
    for (int ni = 0; ni < 2; ++ni)
#pragma unroll
      for (int ks = 0; ks < 2; ++ks) {
        int row = wn * 32 + ni * 16 + l15;
        int ch = (ks * 4 + lg) ^ (l15 & 7);
        bfr[ni][ks] = *(const bf16x8*)(sB + row * 128 + ch * 16);
      }
#pragma unroll
    for (int ks = 0; ks < 2; ++ks)
#pragma unroll
      for (int mi = 0; mi < 2; ++mi)
#pragma unroll
        for (int ni = 0; ni < 2; ++ni)
          acc[mi][ni] = __builtin_amdgcn_mfma_f32_16x16x32_bf16(
              af[mi][ks], bfr[ni][ks], acc[mi][ni], 0, 0, 0);
  };

  stage(0, 0);
  __syncthreads();
  int cur = 0;
  for (int kt = 0; kt < nkt; ++kt) {
    if (kt + 1 < nkt) stage(cur ^ 1, kt + 1);
    compute(cur);
    __syncthreads();
    cur ^= 1;
  }

  float bv0 = bias[n0 + wn * 32 + l15];
  float bv1 = bias[n0 + wn * 32 + 16 + l15];
#pragma unroll
  for (int mi = 0; mi < 2; ++mi)
#pragma unroll
    for (int ni = 0; ni < 2; ++ni) {
      float bv = ni ? bv1 : bv0;
#pragma unroll
      for (int j = 0; j < 4; ++j) {
        int m = m0 + wm * 32 + mi * 16 + lg * 4 + j;   // C/D: row=(lane>>4)*4+reg
        int n = n0 + wn * 32 + ni * 16 + l15;          //      col=lane&15
        out[(size_t)m * F + n] = acc[mi][ni][j] + bv;
      }
    }
}

// ---------------------------------------------------------------------------
// logdet[b,i,o] = log( sum_p exp_blocks[i,o,p] * exp(grad[b,i,p]) )
// ---------------------------------------------------------------------------
__global__ __launch_bounds__(256) void logdet_kernel(
    const float* __restrict__ grad, const float* __restrict__ exp_blocks,
    float* __restrict__ ld)
{
  __shared__ float eb[32][33];
  __shared__ float eg[8][32];
  int i = blockIdx.x & 63;
  int bg = blockIdx.x >> 6;
  int tid = threadIdx.x;
  for (int t = tid; t < 1024; t += 256) {
    eb[t >> 5][t & 31] = exp_blocks[(size_t)i * 1024 + t];
  }
  int pair = tid >> 5, p = tid & 31;
  int b = bg * 8 + pair;
  eg[pair][p] = __expf(grad[((size_t)b * 64 + i) * 32 + p]);
  __syncthreads();
  int o = p;
  float s = 0.f;
#pragma unroll
  for (int q = 0; q < 32; ++q) s += eb[o][q] * eg[pair][q];
  ld[((size_t)b * 64 + i) * 32 + o] = __logf(s);
}

// ---------------------------------------------------------------------------
extern "C" void kernel_launch(void* const* d_in, const int* in_sizes, int n_in,
                              void* d_out, int out_size, void* d_ws, size_t ws_size,
                              hipStream_t stream)
{
  const float* inputs = (const float*)d_in[0];
  const float* grad   = (const float*)d_in[1];
  const float* weight = (const float*)d_in[2];
  const float* dw     = (const float*)d_in[3];
  const float* bias   = (const float*)d_in[4];

  float* out = (float*)d_out;                  // 1024*2048
  float* ld  = out + (size_t)BATCH * F;        // 1024*64*32

  unsigned short* w_n  = (unsigned short*)d_ws;            // 8 MiB
  unsigned short* a_bf = w_n + (size_t)F * F;              // 4 MiB
  float* exp_blocks    = (float*)(a_bf + (size_t)BATCH * F); // 256 KiB

  convert_kernel<<<BATCH * F / 2048, 256, 0, stream>>>(inputs, a_bf);
  prep_kernel<<<F, 256, 0, stream>>>(weight, dw, w_n, exp_blocks);
  gemm_kernel<<<512, 256, 0, stream>>>(a_bf, w_n, bias, out);
  logdet_kernel<<<64 * 128, 256, 0, stream>>>(grad, exp_blocks, ld);
}

// Round 3
// 106.628 us; speedup vs baseline: 2.7405x; 1.1286x over previous
//
#include <hip/hip_runtime.h>

#define F 2048
#define BATCH 1024

typedef short bf16x8 __attribute__((ext_vector_type(8)));
typedef float f32x4 __attribute__((ext_vector_type(4)));
typedef unsigned short u16x4 __attribute__((ext_vector_type(4)));

// round-to-nearest-even f32 -> bf16 (bit trick, finite values only)
__device__ __forceinline__ unsigned short f2bf(float f) {
  unsigned u = __builtin_bit_cast(unsigned, f);
  unsigned r = (u + 0x7fffu + ((u >> 16) & 1u)) >> 16;
  return (unsigned short)r;
}

__device__ __forceinline__ void gload_lds16(const void* g, void* l) {
  __builtin_amdgcn_global_load_lds(
      (const __attribute__((address_space(1))) unsigned int*)g,
      (__attribute__((address_space(3))) unsigned int*)l,
      16, 0, 0);
}

// ---------------------------------------------------------------------------
// fused prep+convert.
// blocks [0,1024): convert inputs f32 -> bf16, 2048 elems/block.
// blocks [1024,1536): prep, one wave per weight row (4 rows/block):
//   w[c] = exp(weight[r,c]) in diag block, weight[r,c] below, 0 above
//   wsn = sum w^2 (shfl reduce); w_n bf16 written for c < (r&~63)+64
//   exp_blocks[r,p] = exp(dw[r] + weight[r,i*32+p] - 0.5*log(wsn))
// ---------------------------------------------------------------------------
__global__ __launch_bounds__(256) void prep_convert_kernel(
    const float* __restrict__ inputs, unsigned short* __restrict__ a_bf,
    const float* __restrict__ weight, const float* __restrict__ dw,
    unsigned short* __restrict__ w_n, float* __restrict__ exp_blocks)
{
  int bid = blockIdx.x;
  if (bid < 1024) {
    int idx = bid * 2048 + threadIdx.x * 8;
    float4 v0 = *(const float4*)(inputs + idx);
    float4 v1 = *(const float4*)(inputs + idx + 4);
    union { unsigned short s[8]; bf16x8 v; } o;
    o.s[0] = f2bf(v0.x); o.s[1] = f2bf(v0.y); o.s[2] = f2bf(v0.z); o.s[3] = f2bf(v0.w);
    o.s[4] = f2bf(v1.x); o.s[5] = f2bf(v1.y); o.s[6] = f2bf(v1.z); o.s[7] = f2bf(v1.w);
    *(bf16x8*)(a_bf + idx) = o.v;
    return;
  }
  int rb = bid - 1024;
  int lane = threadIdx.x & 63;
  int r = rb * 4 + (threadIdx.x >> 6);
  int i = r >> 5;
  int lim = (i + 1) * 32;        // multiple of 32
  int wlim = (r & ~63) + 64;     // multiple of 64
  int d0 = i * 32;               // diag block start (multiple of 32)
  const float* wrow = weight + (size_t)r * F;

  float ss = 0.f;
  for (int j = lane; j < lim / 4; j += 64) {
    float4 v = ((const float4*)wrow)[j];
    if (j * 4 >= d0) {           // 4-aligned groups are uniform vs d0
      v.x = __expf(v.x); v.y = __expf(v.y); v.z = __expf(v.z); v.w = __expf(v.w);
    }
    ss += v.x * v.x + v.y * v.y + v.z * v.z + v.w * v.w;
  }
#pragma unroll
  for (int d = 32; d > 0; d >>= 1) ss += __shfl_xor(ss, d, 64);

  float dwr = dw[r];
  float scale = __expf(dwr) * rsqrtf(ss);
  float halflog = 0.5f * __logf(ss);

  unsigned short* onrow = w_n + (size_t)r * F;
  for (int j = lane; j < wlim / 4; j += 64) {
    u16x4 o = {0, 0, 0, 0};
    if (j * 4 < lim) {
      float4 v = ((const float4*)wrow)[j];
      if (j * 4 >= d0) {
        v.x = __expf(v.x); v.y = __expf(v.y); v.z = __expf(v.z); v.w = __expf(v.w);
      }
      o[0] = f2bf(scale * v.x); o[1] = f2bf(scale * v.y);
      o[2] = f2bf(scale * v.z); o[3] = f2bf(scale * v.w);
    }
    *(u16x4*)(onrow + j * 4) = o;
  }
  if (lane < 32) {
    exp_blocks[(size_t)r * 32 + lane] = __expf(dwr + wrow[d0 + lane] - halflog);
  }
}

// ---------------------------------------------------------------------------
// gemm (bf16 MFMA): out[b,r] = sum_c A[b,c]*W[r,c] + bias[r]   (NT, K-major)
// 64x64 tile, BK=64, 4 waves x (32x32, 2x2 frags of 16x16x32).
// 3-stage LDS pipeline, counted vmcnt (4 gload_lds/thread/stage -> vmcnt(8)
// steady state), raw s_barrier (no vmcnt(0) drain). XOR-swizzled staging.
// Triangular K: tile tn runs tn+1 K-steps; tm&8 flip pairs complementary
// tiles on the same CU (blocks i, i+256 -> tn + tn' = 31).
// ---------------------------------------------------------------------------
__global__ __launch_bounds__(256) void gemm_kernel(
    const unsigned short* __restrict__ A, const unsigned short* __restrict__ W,
    const float* __restrict__ bias, float* __restrict__ out)
{
  __shared__ char smem[3][2][8192];  // [stage][A/B][64 rows x 128 B]

  int id = blockIdx.x;
  int tm = id >> 5;
  int tn_raw = id & 31;
  int tn = (tm & 8) ? (31 - tn_raw) : tn_raw;
  int m0 = tm * 64, n0 = tn * 64;
  int nkt = tn + 1;

  int tid = threadIdx.x;
  int lane = tid & 63, wid = tid >> 6;
  int wm = wid >> 1, wn = wid & 1;
  int l15 = lane & 15, lg = lane >> 4;

  int srow = lane >> 3;
  int schunk = (lane & 7) ^ (srow & 7);

  auto stage = [&](int buf, int kt) {
    size_t kb = (size_t)kt * 128;
#pragma unroll
    for (int e = 0; e < 2; ++e) {
      int s = wid * 2 + e;
      int row = s * 8 + srow;
      const char* ga = (const char*)A + (size_t)(m0 + row) * (F * 2) + kb + schunk * 16;
      gload_lds16(ga, &smem[buf][0][s * 1024]);
      const char* gb = (const char*)W + (size_t)(n0 + row) * (F * 2) + kb + schunk * 16;
      gload_lds16(gb, &smem[buf][1][s * 1024]);
    }
  };

  f32x4 acc[2][2] = {};

  auto compute = [&](int buf) {
    const char* sA = smem[buf][0];
    const char* sB = smem[buf][1];
    bf16x8 af[2][2], bfr[2][2];
#pragma unroll
    for (int mi = 0; mi < 2; ++mi)
#pragma unroll
      for (int ks = 0; ks < 2; ++ks) {
        int row = wm * 32 + mi * 16 + l15;
        int ch = (ks * 4 + lg) ^ (l15 & 7);
        af[mi][ks] = *(const bf16x8*)(sA + row * 128 + ch * 16);
      }
#pragma unroll
    for (int ni = 0; ni < 2; ++ni)
#pragma unroll
      for (int ks = 0; ks < 2; ++ks) {
        int row = wn * 32 + ni * 16 + l15;
        int ch = (ks * 4 + lg) ^ (l15 & 7);
        bfr[ni][ks] = *(const bf16x8*)(sB + row * 128 + ch * 16);
      }
#pragma unroll
    for (int ks = 0; ks < 2; ++ks)
#pragma unroll
      for (int mi = 0; mi < 2; ++mi)
#pragma unroll
        for (int ni = 0; ni < 2; ++ni)
          acc[mi][ni] = __builtin_amdgcn_mfma_f32_16x16x32_bf16(
              af[mi][ks], bfr[ni][ks], acc[mi][ni], 0, 0, 0);
  };

  // 3-deep pipeline: stages kt+1, kt+2 stay in flight across barriers.
  stage(0, 0);
  if (nkt > 1) stage(1, 1);
  for (int kt = 0; kt < nkt; ++kt) {
    if (kt + 2 < nkt) stage((kt + 2) % 3, kt + 2);
    int rem = nkt - 1 - kt;
    if (rem >= 2)      asm volatile("s_waitcnt vmcnt(8)" ::: "memory");
    else if (rem == 1) asm volatile("s_waitcnt vmcnt(4)" ::: "memory");
    else               asm volatile("s_waitcnt vmcnt(0)" ::: "memory");
    __builtin_amdgcn_s_barrier();   // all waves: stage kt resident in LDS
    compute(kt % 3);
    __builtin_amdgcn_s_barrier();   // reads of buf kt done before overwrite
  }

  float bv0 = bias[n0 + wn * 32 + l15];
  float bv1 = bias[n0 + wn * 32 + 16 + l15];
#pragma unroll
  for (int mi = 0; mi < 2; ++mi)
#pragma unroll
    for (int ni = 0; ni < 2; ++ni) {
      float bv = ni ? bv1 : bv0;
#pragma unroll
      for (int j = 0; j < 4; ++j) {
        int m = m0 + wm * 32 + mi * 16 + lg * 4 + j;
        int n = n0 + wn * 32 + ni * 16 + l15;
        out[(size_t)m * F + n] = acc[mi][ni][j] + bv;
      }
    }
}

// ---------------------------------------------------------------------------
// logdet[b,i,o] = log( sum_p exp_blocks[i,o,p] * exp(grad[b,i,p]) )
// Block handles one i and 32 batches (eb L2 traffic balanced with grad).
// ---------------------------------------------------------------------------
__global__ __launch_bounds__(256) void logdet_kernel(
    const float* __restrict__ grad, const float* __restrict__ exp_blocks,
    float* __restrict__ ld)
{
  __shared__ float eb[32][33];
  __shared__ float eg[32][32];
  int i = blockIdx.x & 63;
  int b0 = (blockIdx.x >> 6) * 32;
  int tid = threadIdx.x;
  int p = tid & 31, row8 = tid >> 5;

#pragma unroll
  for (int k = 0; k < 4; ++k) {
    int t = tid + k * 256;
    eb[t >> 5][t & 31] = exp_blocks[(size_t)i * 1024 + t];
  }
#pragma unroll
  for (int k = 0; k < 4; ++k) {
    int b = b0 + row8 + 8 * k;
    eg[row8 + 8 * k][p] = __expf(grad[((size_t)b * 64 + i) * 32 + p]);
  }
  __syncthreads();

  int o = p;                      // output column
  float s[4] = {0.f, 0.f, 0.f, 0.f};
#pragma unroll
  for (int q = 0; q < 32; ++q) {
    float e = eb[o][q];
#pragma unroll
    for (int k = 0; k < 4; ++k) s[k] += e * eg[row8 + 8 * k][q];
  }
#pragma unroll
  for (int k = 0; k < 4; ++k) {
    int b = b0 + row8 + 8 * k;
    ld[((size_t)b * 64 + i) * 32 + o] = __logf(s[k]);
  }
}

// ---------------------------------------------------------------------------
extern "C" void kernel_launch(void* const* d_in, const int* in_sizes, int n_in,
                              void* d_out, int out_size, void* d_ws, size_t ws_size,
                              hipStream_t stream)
{
  const float* inputs = (const float*)d_in[0];
  const float* grad   = (const float*)d_in[1];
  const float* weight = (const float*)d_in[2];
  const float* dw     = (const float*)d_in[3];
  const float* bias   = (const float*)d_in[4];

  float* out = (float*)d_out;                  // 1024*2048
  float* ld  = out + (size_t)BATCH * F;        // 1024*64*32

  unsigned short* w_n  = (unsigned short*)d_ws;              // 8 MiB
  unsigned short* a_bf = w_n + (size_t)F * F;                // 4 MiB
  float* exp_blocks    = (float*)(a_bf + (size_t)BATCH * F); // 256 KiB

  prep_convert_kernel<<<1536, 256, 0, stream>>>(inputs, a_bf, weight, dw, w_n, exp_blocks);
  gemm_kernel<<<512, 256, 0, stream>>>(a_bf, w_n, bias, out);
  logdet_kernel<<<64 * 32, 256, 0, stream>>>(grad, exp_blocks, ld);
}

// Round 4
// 106.017 us; speedup vs baseline: 2.7563x; 1.0058x over previous
//
#include <hip/hip_runtime.h>

#define F 2048
#define BATCH 1024

typedef short bf16x8 __attribute__((ext_vector_type(8)));
typedef float f32x4 __attribute__((ext_vector_type(4)));
typedef unsigned short u16x4 __attribute__((ext_vector_type(4)));

// round-to-nearest-even f32 -> bf16 (bit trick, finite values only)
__device__ __forceinline__ unsigned short f2bf(float f) {
  unsigned u = __builtin_bit_cast(unsigned, f);
  unsigned r = (u + 0x7fffu + ((u >> 16) & 1u)) >> 16;
  return (unsigned short)r;
}

__device__ __forceinline__ void gload_lds16(const void* g, void* l) {
  __builtin_amdgcn_global_load_lds(
      (const __attribute__((address_space(1))) unsigned int*)g,
      (__attribute__((address_space(3))) unsigned int*)l,
      16, 0, 0);
}

// ---------------------------------------------------------------------------
// K1: fused prep+convert.
// blocks [0,1024): convert inputs f32 -> bf16, 2048 elems/block.
// blocks [1024,1536): prep, one wave per weight row (4 rows/block):
//   w[c] = exp(weight[r,c]) in diag block, weight[r,c] below, 0 above
//   wsn = sum w^2 (shfl reduce); w_n bf16 written for c < (r&~63)+64
//   exp_blocks[r,p] = exp(dw[r] + weight[r,i*32+p] - 0.5*log(wsn))
// ---------------------------------------------------------------------------
__global__ __launch_bounds__(256) void prep_convert_kernel(
    const float* __restrict__ inputs, unsigned short* __restrict__ a_bf,
    const float* __restrict__ weight, const float* __restrict__ dw,
    unsigned short* __restrict__ w_n, float* __restrict__ exp_blocks)
{
  int bid = blockIdx.x;
  if (bid < 1024) {
    int idx = bid * 2048 + threadIdx.x * 8;
    float4 v0 = *(const float4*)(inputs + idx);
    float4 v1 = *(const float4*)(inputs + idx + 4);
    union { unsigned short s[8]; bf16x8 v; } o;
    o.s[0] = f2bf(v0.x); o.s[1] = f2bf(v0.y); o.s[2] = f2bf(v0.z); o.s[3] = f2bf(v0.w);
    o.s[4] = f2bf(v1.x); o.s[5] = f2bf(v1.y); o.s[6] = f2bf(v1.z); o.s[7] = f2bf(v1.w);
    *(bf16x8*)(a_bf + idx) = o.v;
    return;
  }
  int rb = bid - 1024;
  int lane = threadIdx.x & 63;
  int r = rb * 4 + (threadIdx.x >> 6);
  int i = r >> 5;
  int lim = (i + 1) * 32;        // multiple of 32
  int wlim = (r & ~63) + 64;     // multiple of 64
  int d0 = i * 32;               // diag block start (multiple of 32)
  const float* wrow = weight + (size_t)r * F;

  float ss = 0.f;
  for (int j = lane; j < lim / 4; j += 64) {
    float4 v = ((const float4*)wrow)[j];
    if (j * 4 >= d0) {           // 4-aligned groups are uniform vs d0
      v.x = __expf(v.x); v.y = __expf(v.y); v.z = __expf(v.z); v.w = __expf(v.w);
    }
    ss += v.x * v.x + v.y * v.y + v.z * v.z + v.w * v.w;
  }
#pragma unroll
  for (int d = 32; d > 0; d >>= 1) ss += __shfl_xor(ss, d, 64);

  float dwr = dw[r];
  float scale = __expf(dwr) * rsqrtf(ss);
  float halflog = 0.5f * __logf(ss);

  unsigned short* onrow = w_n + (size_t)r * F;
  for (int j = lane; j < wlim / 4; j += 64) {
    u16x4 o = {0, 0, 0, 0};
    if (j * 4 < lim) {
      float4 v = ((const float4*)wrow)[j];
      if (j * 4 >= d0) {
        v.x = __expf(v.x); v.y = __expf(v.y); v.z = __expf(v.z); v.w = __expf(v.w);
      }
      o[0] = f2bf(scale * v.x); o[1] = f2bf(scale * v.y);
      o[2] = f2bf(scale * v.z); o[3] = f2bf(scale * v.w);
    }
    *(u16x4*)(onrow + j * 4) = o;
  }
  if (lane < 32) {
    exp_blocks[(size_t)r * 32 + lane] = __expf(dwr + wrow[d0 + lane] - halflog);
  }
}

// ---------------------------------------------------------------------------
// K2: fused gemm (bf16 MFMA) + logdet.
// gemm: out[b,r] = sum_c A[b,c]*W[r,c] + bias[r]   (NT, K-major)
//   64x64 tile, BK=64, 4 waves x (32x32, 2x2 frags of 16x16x32).
//   3-stage LDS pipeline, counted vmcnt, raw s_barrier. XOR-swizzled staging.
//   Triangular K: tile tn runs tn+1 K-steps; tm&8 flip pairs complementary
//   tiles on the same CU (blocks i, i+256 -> tn + tn' = 31).
// logdet (after gemm; depends only on exp_blocks from K1):
//   block handles i = bid&63 and 4 batch-groups of 32; eb in LDS reused 4x.
//   ld[b,i,o] = log( sum_p eb[i,o,p] * exp(grad[b,i,p]) )
// ---------------------------------------------------------------------------
__global__ __launch_bounds__(256) void gemm_logdet_kernel(
    const unsigned short* __restrict__ A, const unsigned short* __restrict__ W,
    const float* __restrict__ bias, const float* __restrict__ grad,
    const float* __restrict__ exp_blocks, float* __restrict__ out,
    float* __restrict__ ld)
{
  __shared__ __align__(16) char smem[3 * 16384];  // 48 KiB, overlaid by logdet

  int id = blockIdx.x;
  int tm = id >> 5;
  int tn_raw = id & 31;
  int tn = (tm & 8) ? (31 - tn_raw) : tn_raw;
  int m0 = tm * 64, n0 = tn * 64;
  int nkt = tn + 1;

  int tid = threadIdx.x;
  int lane = tid & 63, wid = tid >> 6;
  int wm = wid >> 1, wn = wid & 1;
  int l15 = lane & 15, lg = lane >> 4;

  int srow = lane >> 3;
  int schunk = (lane & 7) ^ (srow & 7);

  auto stage = [&](int buf, int kt) {
    size_t kb = (size_t)kt * 128;
    char* base = smem + buf * 16384;
#pragma unroll
    for (int e = 0; e < 2; ++e) {
      int s = wid * 2 + e;
      int row = s * 8 + srow;
      const char* ga = (const char*)A + (size_t)(m0 + row) * (F * 2) + kb + schunk * 16;
      gload_lds16(ga, base + s * 1024);
      const char* gb = (const char*)W + (size_t)(n0 + row) * (F * 2) + kb + schunk * 16;
      gload_lds16(gb, base + 8192 + s * 1024);
    }
  };

  f32x4 acc[2][2] = {};

  auto compute = [&](int buf) {
    const char* sA = smem + buf * 16384;
    const char* sB = sA + 8192;
    bf16x8 af[2][2], bfr[2][2];
#pragma unroll
    for (int mi = 0; mi < 2; ++mi)
#pragma unroll
      for (int ks = 0; ks < 2; ++ks) {
        int row = wm * 32 + mi * 16 + l15;
        int ch = (ks * 4 + lg) ^ (l15 & 7);
        af[mi][ks] = *(const bf16x8*)(sA + row * 128 + ch * 16);
      }
#pragma unroll
    for (int ni = 0; ni < 2; ++ni)
#pragma unroll
      for (int ks = 0; ks < 2; ++ks) {
        int row = wn * 32 + ni * 16 + l15;
        int ch = (ks * 4 + lg) ^ (l15 & 7);
        bfr[ni][ks] = *(const bf16x8*)(sB + row * 128 + ch * 16);
      }
#pragma unroll
    for (int ks = 0; ks < 2; ++ks)
#pragma unroll
      for (int mi = 0; mi < 2; ++mi)
#pragma unroll
        for (int ni = 0; ni < 2; ++ni)
          acc[mi][ni] = __builtin_amdgcn_mfma_f32_16x16x32_bf16(
              af[mi][ks], bfr[ni][ks], acc[mi][ni], 0, 0, 0);
  };

  // 3-deep pipeline: stages kt+1, kt+2 stay in flight across barriers.
  stage(0, 0);
  if (nkt > 1) stage(1, 1);
  for (int kt = 0; kt < nkt; ++kt) {
    if (kt + 2 < nkt) stage((kt + 2) % 3, kt + 2);
    int rem = nkt - 1 - kt;
    if (rem >= 2)      asm volatile("s_waitcnt vmcnt(8)" ::: "memory");
    else if (rem == 1) asm volatile("s_waitcnt vmcnt(4)" ::: "memory");
    else               asm volatile("s_waitcnt vmcnt(0)" ::: "memory");
    __builtin_amdgcn_s_barrier();   // stage kt resident in LDS
    compute(kt % 3);
    __builtin_amdgcn_s_barrier();   // reads of buf kt done before overwrite
  }
  // After the final s_barrier no wave touches gemm smem again (each wave's
  // ds_reads retired via lgkmcnt before its MFMAs, which precede the barrier).

  float bv0 = bias[n0 + wn * 32 + l15];
  float bv1 = bias[n0 + wn * 32 + 16 + l15];
#pragma unroll
  for (int mi = 0; mi < 2; ++mi)
#pragma unroll
    for (int ni = 0; ni < 2; ++ni) {
      float bv = ni ? bv1 : bv0;
#pragma unroll
      for (int j = 0; j < 4; ++j) {
        int m = m0 + wm * 32 + mi * 16 + lg * 4 + j;   // C/D: row=(lane>>4)*4+reg
        int n = n0 + wn * 32 + ni * 16 + l15;          //      col=lane&15
        out[(size_t)m * F + n] = acc[mi][ni][j] + bv;
      }
    }

  // ---------------- logdet ----------------
  float* eb = (float*)smem;            // [32][36] padded (16B-aligned rows)
  float* eg = (float*)(smem + 32 * 36 * 4);  // [32][32]
  int li = id & 63;
  int bg0 = (id >> 6) * 4;             // 4 batch-groups of 32
  int p = tid & 31, row8 = tid >> 5;   // p = output col o; row8 in 0..7

#pragma unroll
  for (int k = 0; k < 4; ++k) {
    int t = tid + k * 256;
    eb[(t >> 5) * 36 + (t & 31)] = exp_blocks[(size_t)li * 1024 + t];
  }

#pragma unroll
  for (int g4 = 0; g4 < 4; ++g4) {
    int b0 = (bg0 + g4) * 32;
    __syncthreads();                   // eb visible / prev-iter eg reads done
#pragma unroll
    for (int k = 0; k < 4; ++k) {
      int b = b0 + row8 + 8 * k;
      eg[(row8 + 8 * k) * 32 + p] = __expf(grad[((size_t)b * 64 + li) * 32 + p]);
    }
    __syncthreads();
    float s[4] = {0.f, 0.f, 0.f, 0.f};
#pragma unroll
    for (int q4 = 0; q4 < 8; ++q4) {
      f32x4 e = *(const f32x4*)(eb + p * 36 + q4 * 4);
#pragma unroll
      for (int k = 0; k < 4; ++k) {
        f32x4 g = *(const f32x4*)(eg + (row8 + 8 * k) * 32 + q4 * 4);  // broadcast
        s[k] += e[0] * g[0] + e[1] * g[1] + e[2] * g[2] + e[3] * g[3];
      }
    }
#pragma unroll
    for (int k = 0; k < 4; ++k) {
      int b = b0 + row8 + 8 * k;
      ld[((size_t)b * 64 + li) * 32 + p] = __logf(s[k]);
    }
  }
}

// ---------------------------------------------------------------------------
extern "C" void kernel_launch(void* const* d_in, const int* in_sizes, int n_in,
                              void* d_out, int out_size, void* d_ws, size_t ws_size,
                              hipStream_t stream)
{
  const float* inputs = (const float*)d_in[0];
  const float* grad   = (const float*)d_in[1];
  const float* weight = (const float*)d_in[2];
  const float* dw     = (const float*)d_in[3];
  const float* bias   = (const float*)d_in[4];

  float* out = (float*)d_out;                  // 1024*2048
  float* ld  = out + (size_t)BATCH * F;        // 1024*64*32

  unsigned short* w_n  = (unsigned short*)d_ws;              // 8 MiB
  unsigned short* a_bf = w_n + (size_t)F * F;                // 4 MiB
  float* exp_blocks    = (float*)(a_bf + (size_t)BATCH * F); // 256 KiB

  prep_convert_kernel<<<1536, 256, 0, stream>>>(inputs, a_bf, weight, dw, w_n, exp_blocks);
  gemm_logdet_kernel<<<512, 256, 0, stream>>>(a_bf, w_n, bias, grad, exp_blocks, out, ld);
}